// Round 13
// baseline (590.560 us; speedup 1.0000x reference)
//
#include <hip/hip_runtime.h>
#include <hip/hip_fp16.h>
#include <hip/hip_cooperative_groups.h>

namespace cg = cooperative_groups;

#define NEG_SLOPE 0.2f

static inline int cdiv(long long a, long long b) { return (int)((a + b - 1) / b); }

typedef _Float16 f16x8 __attribute__((ext_vector_type(8)));
typedef float f32x4 __attribute__((ext_vector_type(4)));

union h4u {
    float2  f2;
    __half2 h2[2];
};

__device__ __forceinline__ void load_sd(const void* ei_raw, int is64, int e, int E_,
                                        int& s, int& d)
{
    if (is64) {
        const long long* p = (const long long*)ei_raw;
        s = (int)p[e];
        d = (int)p[E_ + e];
    } else {
        const int* p = (const int*)ei_raw;
        s = p[e];
        d = p[E_ + e];
    }
}

__device__ __forceinline__ int wave_incl_scan(int v)
{
    int lane = threadIdx.x & 63;
#pragma unroll
    for (int off = 1; off < 64; off <<= 1) {
        int t = __shfl_up(v, off);
        if (lane >= off) v += t;
    }
    return v;
}

// ---------------------------------------------------------------------------
// COOPERATIVE CSR KERNEL — replaces prep/hist/scan_part/scan_add/scatter
// (5 dispatches -> 1). Phases separated by grid.sync():
//   0: deg zero + W fp32->fp16 transposes + per-block int64 probe
//   1: hist (4-deep batched atomics; rank saved -> atomic-free scatter)
//   2: per-chunk exclusive scan (chunk = cdiv(n, gridDim)) -> bsum
//   3: chunk-offset add (parallel masked reduction of bsum); start[n] = E
//   4: scatter (pure permutation, nontemporal ushort stores)
// ---------------------------------------------------------------------------
__global__ __launch_bounds__(256) void csr_kernel(
    const void* __restrict__ ei, int E_, int n,
    int* __restrict__ deg,
    unsigned short* __restrict__ s16, unsigned short* __restrict__ d16,
    unsigned short* __restrict__ r16,
    int* __restrict__ start, int* __restrict__ bsum,
    unsigned short* __restrict__ sorted_src,
    const float* __restrict__ W1, __half* __restrict__ Wt1,
    const float* __restrict__ W2, __half* __restrict__ Wt2,
    const float* __restrict__ W3, __half* __restrict__ Wt3)
{
    cg::grid_group grid = cg::this_grid();
    const int nB    = gridDim.x;
    const int gsize = nB * 256;
    const int gtid  = blockIdx.x * 256 + threadIdx.x;

    // ---- phase 0 ----
    for (int i = gtid; i < n; i += gsize) deg[i] = 0;
    for (int i = gtid; i < 128 * 32; i += gsize) {
        int k = i / 32, c = i % 32;
        Wt1[c * 128 + k] = __float2half(W1[i]);
    }
    for (int i = gtid; i < 32 * 128; i += gsize) {
        int k = i / 128, c = i % 128;
        Wt2[c * 32 + k] = __float2half(W2[i]);
    }
    for (int i = gtid; i < 128 * 128; i += gsize) {
        int k = i / 128, c = i % 128;
        Wt3[c * 128 + k] = __float2half(W3[i]);
    }

    // per-block int64 probe (same 512 entries for all blocks -> consistent)
    __shared__ int bad_sh;
    if (threadIdx.x == 0) bad_sh = 0;
    __syncthreads();
    {
        const long long* e64 = (const long long*)ei;
        int cnt = E_ < 512 ? E_ : 512;
        bool ok = true;
        for (int i = threadIdx.x; i < cnt; i += 256) {
            long long v = e64[i];
            if (v < 0 || v >= n) ok = false;
        }
        if (!ok) atomicAdd(&bad_sh, 1);
    }
    __syncthreads();
    const int is64 = (bad_sh == 0);

    grid.sync();

    // ---- phase 1: hist ----
    for (int base = blockIdx.x * 1024 + threadIdx.x; base < E_; base += gsize * 4) {
        int sj[4], dj[4], rj[4];
        bool v[4];
#pragma unroll
        for (int j = 0; j < 4; j++) {
            int e = base + j * 256;
            v[j] = e < E_;
            if (v[j]) load_sd(ei, is64, e, E_, sj[j], dj[j]);
        }
#pragma unroll
        for (int j = 0; j < 4; j++) {
            int e = base + j * 256;
            if (v[j]) {
                s16[e] = (unsigned short)sj[j];
                d16[e] = (unsigned short)dj[j];
            }
        }
#pragma unroll
        for (int j = 0; j < 4; j++) {
            if (v[j]) rj[j] = atomicAdd(deg + dj[j], 1);
        }
#pragma unroll
        for (int j = 0; j < 4; j++) {
            int e = base + j * 256;
            if (v[j]) r16[e] = (unsigned short)rj[j];
        }
    }

    grid.sync();

    // ---- phase 2: per-chunk exclusive scan ----
    const int C  = (n + nB - 1) / nB;
    const int c0 = blockIdx.x * C;
    const int c1 = (c0 + C) < n ? (c0 + C) : n;
    __shared__ int wsum[4];
    __shared__ int carry_sh;
    if (threadIdx.x == 0) carry_sh = 0;
    __syncthreads();
    for (int t = c0; t < c1; t += 256) {
        int i = t + threadIdx.x;
        int v = (i < c1) ? deg[i] : 0;
        int incl = wave_incl_scan(v);
        int wid = threadIdx.x >> 6, lane = threadIdx.x & 63;
        if (lane == 63) wsum[wid] = incl;
        __syncthreads();
        int woff = 0;
        for (int w = 0; w < wid; w++) woff += wsum[w];
        int carry = carry_sh;
        int excl = incl - v + woff + carry;
        if (i < c1) start[i] = excl;
        __syncthreads();
        if (threadIdx.x == 255) carry_sh = carry + woff + incl;
        __syncthreads();
    }
    if (threadIdx.x == 0) bsum[blockIdx.x] = carry_sh;

    grid.sync();

    // ---- phase 3: add chunk offsets ----
    __shared__ int red[256];
    {
        int partial = 0;
        for (int j = threadIdx.x; j < blockIdx.x; j += 256) partial += bsum[j];
        red[threadIdx.x] = partial;
        __syncthreads();
        for (int s = 128; s > 0; s >>= 1) {
            if (threadIdx.x < s) red[threadIdx.x] += red[threadIdx.x + s];
            __syncthreads();
        }
    }
    int off0 = red[0];
    for (int i = c0 + threadIdx.x; i < c1; i += 256) start[i] += off0;
    if (blockIdx.x == 0 && threadIdx.x == 0) start[n] = E_;  // total edge count

    grid.sync();

    // ---- phase 4: scatter ----
    for (int base = blockIdx.x * 1024 + threadIdx.x; base < E_; base += gsize * 4) {
        int sj[4], dj[4], rj[4];
        bool v[4];
#pragma unroll
        for (int j = 0; j < 4; j++) {
            int e = base + j * 256;
            v[j] = e < E_;
            sj[j] = v[j] ? (int)s16[e] : 0;
            dj[j] = v[j] ? (int)d16[e] : 0;
            rj[j] = v[j] ? (int)r16[e] : 0;
        }
        int pj[4];
#pragma unroll
        for (int j = 0; j < 4; j++) {
            if (v[j]) pj[j] = start[dj[j]] + rj[j];
        }
#pragma unroll
        for (int j = 0; j < 4; j++) {
            if (v[j])
                __builtin_nontemporal_store((unsigned short)sj[j], sorted_src + pj[j]);
        }
    }
}

// ---------------------------------------------------------------------------
// MFMA GEMM + fused attention epilogue (Round-10 structure, verified).
// A16=0: stage A from fp32 with in-register convert (layer 1).
// ---------------------------------------------------------------------------
template <int K, int NOUT, int A16>
__global__ __launch_bounds__(256) void gemm_mfma_kernel(
    const void* __restrict__ xin, const __half* __restrict__ Wt,
    const float* __restrict__ att_s, const float* __restrict__ att_d,
    __half* __restrict__ h, float* __restrict__ a_s, float* __restrict__ a_d, int n)
{
    constexpr int KC = 32;
    constexpr int NT = NOUT / 16;
    constexpr int XP = KC + 8;
    constexpr int HP = NOUT + 8;
    constexpr int C  = NOUT / 4;

    __shared__ _Float16 Xs[64 * XP];
    __shared__ _Float16 Ws[NOUT * XP];
    __shared__ _Float16 Hs[64 * HP];
    __shared__ float As[NOUT], Ad[NOUT];

    const int tid  = threadIdx.x;
    const int nb   = blockIdx.x * 64;
    const int wave = tid >> 6, lane = tid & 63;
    const int m16  = lane & 15, quad = lane >> 4;

    if (tid < NOUT) { As[tid] = att_s[tid]; Ad[tid] = att_d[tid]; }

    f32x4 acc[NT];
#pragma unroll
    for (int t = 0; t < NT; t++) acc[t] = (f32x4){0.f, 0.f, 0.f, 0.f};

    for (int kc = 0; kc < K; kc += KC) {
        {
            int node = tid >> 2, seg = tid & 3;
            int gn = nb + node;
            f16x8 v = {0, 0, 0, 0, 0, 0, 0, 0};
            if (gn < n) {
                if (A16) {
                    v = *(const f16x8*)((const __half*)xin + (size_t)gn * K + kc +
                                        seg * 8);
                } else {
                    const float4* p =
                        (const float4*)((const float*)xin + (size_t)gn * K + kc + seg * 8);
                    float4 a = p[0], b = p[1];
                    v = (f16x8){(_Float16)a.x, (_Float16)a.y, (_Float16)a.z,
                                (_Float16)a.w, (_Float16)b.x, (_Float16)b.y,
                                (_Float16)b.z, (_Float16)b.w};
                }
            }
            *(f16x8*)&Xs[node * XP + seg * 8] = v;
        }
        for (int u = tid; u < NOUT * 4; u += 256) {
            int col = u >> 2, seg = u & 3;
            *(f16x8*)&Ws[col * XP + seg * 8] =
                *(const f16x8*)(Wt + (size_t)col * K + kc + seg * 8);
        }
        __syncthreads();

        f16x8 a = *(const f16x8*)&Xs[(wave * 16 + m16) * XP + quad * 8];
#pragma unroll
        for (int t = 0; t < NT; t++) {
            f16x8 b = *(const f16x8*)&Ws[(t * 16 + m16) * XP + quad * 8];
            acc[t] = __builtin_amdgcn_mfma_f32_16x16x32_f16(a, b, acc[t], 0, 0, 0);
        }
        __syncthreads();
    }

#pragma unroll
    for (int t = 0; t < NT; t++) {
#pragma unroll
        for (int r = 0; r < 4; r++) {
            int row = wave * 16 + quad * 4 + r;
            Hs[row * HP + t * 16 + m16] = (_Float16)acc[t][r];
        }
    }
    __syncthreads();

    for (int u = tid; u < 64 * NOUT / 8; u += 256) {
        int row = u / (NOUT / 8), seg = u % (NOUT / 8);
        int gn = nb + row;
        if (gn < n)
            *(f16x8*)(h + (size_t)gn * NOUT + seg * 8) =
                *(const f16x8*)&Hs[row * HP + seg * 8];
    }

    {
        int node = tid >> 2, head = tid & 3;
        int gn = nb + node;
        const _Float16* hr = &Hs[node * HP + head * C];
        float s1 = 0.f, s2 = 0.f;
#pragma unroll 4
        for (int c = 0; c < C; c++) {
            float v = (float)hr[c];
            s1 += v * As[head * C + c];
            s2 += v * Ad[head * C + c];
        }
        if (gn < n) {
            a_s[gn * 4 + head] = s1;
            a_d[gn * 4 + head] = s2;
        }
    }
}

// ---------------------------------------------------------------------------
// SINGLE-SWEEP fused softmax+aggregation, F = 128 (layers 2/3). 32 thr/node,
// 8 nodes/block; 16-deep gather pipeline (+4-deep and scalar remainders).
// MODE 0: +bias, ELU -> fp16. MODE 1: head-mean, +bias -> fp32.
// ---------------------------------------------------------------------------
template <int MODE>
__global__ __launch_bounds__(256) void gat_agg128_kernel(
    const int* __restrict__ start, const unsigned short* __restrict__ ss,
    const __half* __restrict__ h, const float* __restrict__ a_s,
    const float* __restrict__ a_d, const float* __restrict__ bias,
    void* __restrict__ out, int n)
{
    int local = threadIdx.x >> 5;
    int q     = threadIdx.x & 31;
    int node  = blockIdx.x * 8 + local;
    bool active = node < n;
    int s0 = 0, s1 = 0;
    if (active) { s0 = start[node]; s1 = start[node + 1]; }
    int head = q >> 3;
    float adh = active ? a_d[node * 4 + head] : 0.f;
    const float2* __restrict__ h2 = (const float2*)h + q;

    float4 acc = make_float4(0.f, 0.f, 0.f, 0.f);
    float sm = 0.f;
    int i = s0;
    for (; i + 16 <= s1; i += 16) {
        int    sj[16];
        float  ej[16];
        float2 rj[16];
#pragma unroll
        for (int j = 0; j < 16; j++) sj[j] = (int)ss[i + j];
#pragma unroll
        for (int j = 0; j < 16; j++) ej[j] = a_s[sj[j] * 4 + head];
#pragma unroll
        for (int j = 0; j < 16; j++) rj[j] = h2[(size_t)sj[j] * 32];
#pragma unroll
        for (int j = 0; j < 16; j++) {
            float e = ej[j] + adh;
            e = e > 0.f ? e : NEG_SLOPE * e;
            float p = __expf(e);
            sm += p;
            h4u u; u.f2 = rj[j];
            float2 lo = __half22float2(u.h2[0]);
            float2 hi = __half22float2(u.h2[1]);
            acc.x += lo.x * p; acc.y += lo.y * p;
            acc.z += hi.x * p; acc.w += hi.y * p;
        }
    }
    for (; i + 4 <= s1; i += 4) {
        int    sj[4];
        float  ej[4];
        float2 rj[4];
#pragma unroll
        for (int j = 0; j < 4; j++) sj[j] = (int)ss[i + j];
#pragma unroll
        for (int j = 0; j < 4; j++) ej[j] = a_s[sj[j] * 4 + head];
#pragma unroll
        for (int j = 0; j < 4; j++) rj[j] = h2[(size_t)sj[j] * 32];
#pragma unroll
        for (int j = 0; j < 4; j++) {
            float e = ej[j] + adh;
            e = e > 0.f ? e : NEG_SLOPE * e;
            float p = __expf(e);
            sm += p;
            h4u u; u.f2 = rj[j];
            float2 lo = __half22float2(u.h2[0]);
            float2 hi = __half22float2(u.h2[1]);
            acc.x += lo.x * p; acc.y += lo.y * p;
            acc.z += hi.x * p; acc.w += hi.y * p;
        }
    }
    for (; i < s1; i++) {
        int s = (int)ss[i];
        float e = a_s[s * 4 + head] + adh;
        e = e > 0.f ? e : NEG_SLOPE * e;
        float p = __expf(e);
        sm += p;
        h4u u; u.f2 = h2[(size_t)s * 32];
        float2 lo = __half22float2(u.h2[0]);
        float2 hi = __half22float2(u.h2[1]);
        acc.x += lo.x * p; acc.y += lo.y * p;
        acc.z += hi.x * p; acc.w += hi.y * p;
    }

    float inv = 1.f / (sm + 1e-16f);
    acc.x *= inv; acc.y *= inv; acc.z *= inv; acc.w *= inv;

    if (MODE == 0) {
        if (active) {
            float4 b4 = ((const float4*)bias)[q];
            float4 v = make_float4(acc.x + b4.x, acc.y + b4.y, acc.z + b4.z,
                                   acc.w + b4.w);
            v.x = v.x > 0.f ? v.x : (__expf(v.x) - 1.f);
            v.y = v.y > 0.f ? v.y : (__expf(v.y) - 1.f);
            v.z = v.z > 0.f ? v.z : (__expf(v.z) - 1.f);
            v.w = v.w > 0.f ? v.w : (__expf(v.w) - 1.f);
            h4u u;
            u.h2[0] = __floats2half2_rn(v.x, v.y);
            u.h2[1] = __floats2half2_rn(v.z, v.w);
            *(float2*)((__half*)out + (size_t)node * 128 + q * 4) = u.f2;
        }
    } else {
        __shared__ float4 sh4[8][33];
        sh4[local][q] = acc;
        __syncthreads();
        if (q < 8 && active) {
            float4 a = sh4[local][q];
            float4 b = sh4[local][q + 8];
            float4 c = sh4[local][q + 16];
            float4 d = sh4[local][q + 24];
            float4 b4 = ((const float4*)bias)[q];
            float4 r = make_float4(0.25f * (a.x + b.x + c.x + d.x) + b4.x,
                                   0.25f * (a.y + b.y + c.y + d.y) + b4.y,
                                   0.25f * (a.z + b.z + c.z + d.z) + b4.z,
                                   0.25f * (a.w + b.w + c.w + d.w) + b4.w);
            *(float4*)((float*)out + (size_t)node * 32 + q * 4) = r;
        }
    }
}

// ---------------------------------------------------------------------------
// SINGLE-SWEEP fused softmax+aggregation, F = 32 (layer 1). 8 thr/node,
// 32 nodes/block, 16-deep pipeline, fp16 out.
// ---------------------------------------------------------------------------
__global__ __launch_bounds__(256) void gat_agg32_kernel(
    const int* __restrict__ start, const unsigned short* __restrict__ ss,
    const __half* __restrict__ h, const float* __restrict__ a_s,
    const float* __restrict__ a_d, const float* __restrict__ bias,
    __half* __restrict__ out, int n)
{
    int local = threadIdx.x >> 3;
    int q     = threadIdx.x & 7;
    int node  = blockIdx.x * 32 + local;
    bool active = node < n;
    int s0 = 0, s1 = 0;
    if (active) { s0 = start[node]; s1 = start[node + 1]; }
    int head = q >> 1;
    float adh = active ? a_d[node * 4 + head] : 0.f;
    const float2* __restrict__ h2 = (const float2*)h + q;

    float4 acc = make_float4(0.f, 0.f, 0.f, 0.f);
    float sm = 0.f;
    int i = s0;
    for (; i + 16 <= s1; i += 16) {
        int    sj[16];
        float  ej[16];
        float2 rj[16];
#pragma unroll
        for (int j = 0; j < 16; j++) sj[j] = (int)ss[i + j];
#pragma unroll
        for (int j = 0; j < 16; j++) ej[j] = a_s[sj[j] * 4 + head];
#pragma unroll
        for (int j = 0; j < 16; j++) rj[j] = h2[(size_t)sj[j] * 8];
#pragma unroll
        for (int j = 0; j < 16; j++) {
            float e = ej[j] + adh;
            e = e > 0.f ? e : NEG_SLOPE * e;
            float p = __expf(e);
            sm += p;
            h4u u; u.f2 = rj[j];
            float2 lo = __half22float2(u.h2[0]);
            float2 hi = __half22float2(u.h2[1]);
            acc.x += lo.x * p; acc.y += lo.y * p;
            acc.z += hi.x * p; acc.w += hi.y * p;
        }
    }
    for (; i + 4 <= s1; i += 4) {
        int    sj[4];
        float  ej[4];
        float2 rj[4];
#pragma unroll
        for (int j = 0; j < 4; j++) sj[j] = (int)ss[i + j];
#pragma unroll
        for (int j = 0; j < 4; j++) ej[j] = a_s[sj[j] * 4 + head];
#pragma unroll
        for (int j = 0; j < 4; j++) rj[j] = h2[(size_t)sj[j] * 8];
#pragma unroll
        for (int j = 0; j < 4; j++) {
            float e = ej[j] + adh;
            e = e > 0.f ? e : NEG_SLOPE * e;
            float p = __expf(e);
            sm += p;
            h4u u; u.f2 = rj[j];
            float2 lo = __half22float2(u.h2[0]);
            float2 hi = __half22float2(u.h2[1]);
            acc.x += lo.x * p; acc.y += lo.y * p;
            acc.z += hi.x * p; acc.w += hi.y * p;
        }
    }
    for (; i < s1; i++) {
        int s = (int)ss[i];
        float e = a_s[s * 4 + head] + adh;
        e = e > 0.f ? e : NEG_SLOPE * e;
        float p = __expf(e);
        sm += p;
        h4u u; u.f2 = h2[(size_t)s * 8];
        float2 lo = __half22float2(u.h2[0]);
        float2 hi = __half22float2(u.h2[1]);
        acc.x += lo.x * p; acc.y += lo.y * p;
        acc.z += hi.x * p; acc.w += hi.y * p;
    }

    if (active) {
        float inv = 1.f / (sm + 1e-16f);
        float4 b4 = ((const float4*)bias)[q];
        float4 v = make_float4(acc.x * inv + b4.x, acc.y * inv + b4.y,
                               acc.z * inv + b4.z, acc.w * inv + b4.w);
        v.x = v.x > 0.f ? v.x : (__expf(v.x) - 1.f);
        v.y = v.y > 0.f ? v.y : (__expf(v.y) - 1.f);
        v.z = v.z > 0.f ? v.z : (__expf(v.z) - 1.f);
        v.w = v.w > 0.f ? v.w : (__expf(v.w) - 1.f);
        h4u u;
        u.h2[0] = __floats2half2_rn(v.x, v.y);
        u.h2[1] = __floats2half2_rn(v.z, v.w);
        *(float2*)(out + (size_t)node * 32 + q * 4) = u.f2;
    }
}

// ---------------------------------------------------------------------------

extern "C" void kernel_launch(void* const* d_in, const int* in_sizes, int n_in,
                              void* d_out, int out_size, void* d_ws, size_t ws_size,
                              hipStream_t stream)
{
    const float* x   = (const float*)d_in[0];
    const void*  ei  = d_in[1];
    const float* W1  = (const float*)d_in[2];
    const float* as1 = (const float*)d_in[3];
    const float* ad1 = (const float*)d_in[4];
    const float* b1  = (const float*)d_in[5];
    const float* W2  = (const float*)d_in[6];
    const float* as2 = (const float*)d_in[7];
    const float* ad2 = (const float*)d_in[8];
    const float* b2  = (const float*)d_in[9];
    const float* W3  = (const float*)d_in[10];
    const float* as3 = (const float*)d_in[11];
    const float* ad3 = (const float*)d_in[12];
    const float* b3  = (const float*)d_in[13];
    float* out = (float*)d_out;

    const int N_ = in_sizes[0] / 128;
    const int E_ = in_sizes[1] / 2;

    char* ws = (char*)d_ws;
    size_t off = 0;
    auto alloc = [&](size_t nbytes) -> void* {
        void* p = ws + off;
        off += (nbytes + 255) & ~(size_t)255;
        return p;
    };
    __half* h          = (__half*)alloc((size_t)N_ * 128 * 2);
    __half* x2h        = (__half*)alloc((size_t)N_ * 32 * 2);
    __half* x3h        = (__half*)alloc((size_t)N_ * 128 * 2);
    __half* Wt1        = (__half*)alloc(128 * 32 * 2);
    __half* Wt2        = (__half*)alloc(32 * 128 * 2);
    __half* Wt3        = (__half*)alloc(128 * 128 * 2);
    float* asrc        = (float*)alloc((size_t)N_ * 4 * 4);
    float* adst        = (float*)alloc((size_t)N_ * 4 * 4);
    int*   deg         = (int*)alloc((size_t)N_ * 4);
    int*   start       = (int*)alloc((size_t)(N_ + 1) * 4);
    unsigned short* sorted_src = (unsigned short*)alloc((size_t)E_ * 2);
    unsigned short* s16        = (unsigned short*)alloc((size_t)E_ * 2);
    unsigned short* d16        = (unsigned short*)alloc((size_t)E_ * 2);
    unsigned short* r16        = (unsigned short*)alloc((size_t)E_ * 2);
    int*   bsum        = (int*)alloc(4096);

    const int gN8  = cdiv(N_, 8);
    const int gN32 = cdiv(N_, 32);
    const int gN64 = cdiv(N_, 64);

    // ---- Cooperative CSR build (prep+hist+scan+scatter in one launch) ----
    {
        int nCsrB = 784;  // 784 x 256 = 200704 threads; 4 waves/blk -> co-resident
        void* cargs[] = {(void*)&ei,  (void*)&E_,  (void*)&N_,   (void*)&deg,
                         (void*)&s16, (void*)&d16, (void*)&r16,  (void*)&start,
                         (void*)&bsum, (void*)&sorted_src,
                         (void*)&W1,  (void*)&Wt1, (void*)&W2,   (void*)&Wt2,
                         (void*)&W3,  (void*)&Wt3};
        hipLaunchCooperativeKernel((void*)csr_kernel, dim3(nCsrB), dim3(256),
                                   cargs, 0, stream);
    }

    // ---- Layer 1: 128 -> [4,8] concat=32, ELU ----
    gemm_mfma_kernel<128, 32, 0><<<gN64, 256, 0, stream>>>(x, Wt1, as1, ad1, h,
                                                           asrc, adst, N_);
    gat_agg32_kernel<<<gN32, 256, 0, stream>>>(start, sorted_src, h, asrc, adst, b1,
                                               x2h, N_);

    // ---- Layer 2: 32 -> [4,32] concat=128, ELU ----
    gemm_mfma_kernel<32, 128, 1><<<gN64, 256, 0, stream>>>(x2h, Wt2, as2, ad2, h,
                                                           asrc, adst, N_);
    gat_agg128_kernel<0><<<gN8, 256, 0, stream>>>(start, sorted_src, h, asrc, adst, b2,
                                                  x3h, N_);

    // ---- Layer 3: 128 -> [4,32] mean=32 ----
    gemm_mfma_kernel<128, 128, 1><<<gN64, 256, 0, stream>>>(x3h, Wt3, as3, ad3, h,
                                                            asrc, adst, N_);
    gat_agg128_kernel<1><<<gN8, 256, 0, stream>>>(start, sorted_src, h, asrc, adst, b3,
                                                  out, N_);
}

// Round 14
// 288.151 us; speedup vs baseline: 2.0495x; 2.0495x over previous
//
#include <hip/hip_runtime.h>
#include <hip/hip_fp16.h>

#define NEG_SLOPE 0.2f

static inline int cdiv(long long a, long long b) { return (int)((a + b - 1) / b); }

typedef _Float16 f16x8 __attribute__((ext_vector_type(8)));
typedef float f32x4 __attribute__((ext_vector_type(4)));

union h4u {
    float2  f2;
    __half2 h2[2];
};

__device__ __forceinline__ void load_sd(const void* ei_raw, int is64, int e, int E_,
                                        int& s, int& d)
{
    if (is64) {
        const long long* p = (const long long*)ei_raw;
        s = (int)p[e];
        d = (int)p[E_ + e];
    } else {
        const int* p = (const int*)ei_raw;
        s = p[e];
        d = p[E_ + e];
    }
}

// ---------------------------------------------------------------------------
// PREP: int64 probe (block 0), deg zero-init, W fp32->fp16 transposes.
// (Round-13 lesson: separate small dispatches beat cooperative grid.sync —
// grid-wide barriers cost ~80 µs each on 8 non-coherent XCDs.)
// ---------------------------------------------------------------------------
__global__ __launch_bounds__(256) void prep_kernel(
    const void* __restrict__ ei, int E_, int n, int* __restrict__ flag,
    int* __restrict__ deg,
    const float* __restrict__ W1, __half* __restrict__ Wt1,
    const float* __restrict__ W2, __half* __restrict__ Wt2,
    const float* __restrict__ W3, __half* __restrict__ Wt3)
{
    int idx = blockIdx.x * 256 + threadIdx.x;

    if (blockIdx.x == 0) {
        __shared__ int bad;
        if (threadIdx.x == 0) bad = 0;
        __syncthreads();
        const long long* e64 = (const long long*)ei;
        int cnt = E_ < 512 ? E_ : 512;
        bool ok = true;
        for (int i = threadIdx.x; i < cnt; i += 256) {
            long long v = e64[i];
            if (v < 0 || v >= n) ok = false;
        }
        if (!ok) atomicAdd(&bad, 1);
        __syncthreads();
        if (threadIdx.x == 0) *flag = (bad == 0) ? 1 : 0;
    }

    if (idx < n) deg[idx] = 0;

    if (idx < 128 * 32) {             // W1: [128][32] -> Wt1[col][128]
        int k = idx / 32, c = idx % 32;
        Wt1[c * 128 + k] = __float2half(W1[idx]);
    }
    if (idx < 32 * 128) {             // W2: [32][128] -> Wt2[col][32]
        int k = idx / 128, c = idx % 128;
        Wt2[c * 32 + k] = __float2half(W2[idx]);
    }
    if (idx < 128 * 128) {            // W3: [128][128] -> Wt3[col][128]
        int k = idx / 128, c = idx % 128;
        Wt3[c * 128 + k] = __float2half(W3[idx]);
    }
}

// ---------------------------------------------------------------------------
// CSR build — ushort edge arrays; rank saved in hist -> atomic-free scatter.
// ---------------------------------------------------------------------------
__global__ __launch_bounds__(256) void hist_kernel(const void* __restrict__ ei_raw,
                                                   const int* __restrict__ flag,
                                                   int* __restrict__ deg,
                                                   unsigned short* __restrict__ s16,
                                                   unsigned short* __restrict__ d16,
                                                   unsigned short* __restrict__ r16,
                                                   int E_)
{
    int base = blockIdx.x * 1024 + threadIdx.x;
    int is64 = *flag;
    int sj[4], dj[4], rj[4];
    bool v[4];
#pragma unroll
    for (int j = 0; j < 4; j++) {
        int e = base + j * 256;
        v[j] = e < E_;
        if (v[j]) load_sd(ei_raw, is64, e, E_, sj[j], dj[j]);
    }
#pragma unroll
    for (int j = 0; j < 4; j++) {
        int e = base + j * 256;
        if (v[j]) {
            s16[e] = (unsigned short)sj[j];
            d16[e] = (unsigned short)dj[j];
        }
    }
#pragma unroll
    for (int j = 0; j < 4; j++) {
        if (v[j]) rj[j] = atomicAdd(deg + dj[j], 1);
    }
#pragma unroll
    for (int j = 0; j < 4; j++) {
        int e = base + j * 256;
        if (v[j]) r16[e] = (unsigned short)rj[j];
    }
}

__device__ __forceinline__ int wave_incl_scan(int v)
{
    int lane = threadIdx.x & 63;
#pragma unroll
    for (int off = 1; off < 64; off <<= 1) {
        int t = __shfl_up(v, off);
        if (lane >= off) v += t;
    }
    return v;
}

__global__ __launch_bounds__(1024) void scan_part_kernel(const int* __restrict__ deg,
                                                         int* __restrict__ start,
                                                         int* __restrict__ bsum, int n)
{
    __shared__ int wsum[16];
    int i = blockIdx.x * 1024 + threadIdx.x;
    int wid = threadIdx.x >> 6, lane = threadIdx.x & 63;
    int v = (i < n) ? deg[i] : 0;
    int incl = wave_incl_scan(v);
    if (lane == 63) wsum[wid] = incl;
    __syncthreads();
    if (wid == 0) {
        int w = (lane < 16) ? wsum[lane] : 0;
        w = wave_incl_scan(w);
        if (lane < 16) wsum[lane] = w;
    }
    __syncthreads();
    int excl = incl - v + (wid ? wsum[wid - 1] : 0);
    if (i < n) start[i] = excl;
    if (threadIdx.x == 1023) bsum[blockIdx.x] = wsum[15];
}

__global__ __launch_bounds__(1024) void scan_add_kernel(const int* __restrict__ deg,
                                                        const int* __restrict__ bsum,
                                                        int* __restrict__ start, int n)
{
    __shared__ int off_sh;
    if (threadIdx.x == 0) {
        int s = 0;
        for (int j = 0; j < blockIdx.x; j++) s += bsum[j];
        off_sh = s;
    }
    __syncthreads();
    int i = blockIdx.x * 1024 + threadIdx.x;
    if (i >= n) return;
    int v = start[i] + off_sh;
    start[i] = v;
    if (i == n - 1) start[n] = v + deg[i];
}

__global__ __launch_bounds__(256) void scatter_kernel(
    const unsigned short* __restrict__ s16, const unsigned short* __restrict__ d16,
    const unsigned short* __restrict__ r16, const int* __restrict__ start,
    unsigned short* __restrict__ sorted_src, int E_)
{
    int base = blockIdx.x * 1024 + threadIdx.x;
    int sj[4], dj[4], rj[4];
    bool v[4];
#pragma unroll
    for (int j = 0; j < 4; j++) {
        int e = base + j * 256;
        v[j] = e < E_;
        sj[j] = v[j] ? (int)s16[e] : 0;
        dj[j] = v[j] ? (int)d16[e] : 0;
        rj[j] = v[j] ? (int)r16[e] : 0;
    }
    int pj[4];
#pragma unroll
    for (int j = 0; j < 4; j++) {
        if (v[j]) pj[j] = start[dj[j]] + rj[j];
    }
#pragma unroll
    for (int j = 0; j < 4; j++) {
        if (v[j])
            __builtin_nontemporal_store((unsigned short)sj[j], sorted_src + pj[j]);
    }
}

// ---------------------------------------------------------------------------
// MFMA GEMM + fused attention epilogue (Round-10 structure, verified).
// A16=0: stage A from fp32 with in-register convert (layer 1).
// ---------------------------------------------------------------------------
template <int K, int NOUT, int A16>
__global__ __launch_bounds__(256) void gemm_mfma_kernel(
    const void* __restrict__ xin, const __half* __restrict__ Wt,
    const float* __restrict__ att_s, const float* __restrict__ att_d,
    __half* __restrict__ h, float* __restrict__ a_s, float* __restrict__ a_d, int n)
{
    constexpr int KC = 32;
    constexpr int NT = NOUT / 16;
    constexpr int XP = KC + 8;
    constexpr int HP = NOUT + 8;
    constexpr int C  = NOUT / 4;

    __shared__ _Float16 Xs[64 * XP];
    __shared__ _Float16 Ws[NOUT * XP];
    __shared__ _Float16 Hs[64 * HP];
    __shared__ float As[NOUT], Ad[NOUT];

    const int tid  = threadIdx.x;
    const int nb   = blockIdx.x * 64;
    const int wave = tid >> 6, lane = tid & 63;
    const int m16  = lane & 15, quad = lane >> 4;

    if (tid < NOUT) { As[tid] = att_s[tid]; Ad[tid] = att_d[tid]; }

    f32x4 acc[NT];
#pragma unroll
    for (int t = 0; t < NT; t++) acc[t] = (f32x4){0.f, 0.f, 0.f, 0.f};

    for (int kc = 0; kc < K; kc += KC) {
        {
            int node = tid >> 2, seg = tid & 3;
            int gn = nb + node;
            f16x8 v = {0, 0, 0, 0, 0, 0, 0, 0};
            if (gn < n) {
                if (A16) {
                    v = *(const f16x8*)((const __half*)xin + (size_t)gn * K + kc +
                                        seg * 8);
                } else {
                    const float4* p =
                        (const float4*)((const float*)xin + (size_t)gn * K + kc + seg * 8);
                    float4 a = p[0], b = p[1];
                    v = (f16x8){(_Float16)a.x, (_Float16)a.y, (_Float16)a.z,
                                (_Float16)a.w, (_Float16)b.x, (_Float16)b.y,
                                (_Float16)b.z, (_Float16)b.w};
                }
            }
            *(f16x8*)&Xs[node * XP + seg * 8] = v;
        }
        for (int u = tid; u < NOUT * 4; u += 256) {
            int col = u >> 2, seg = u & 3;
            *(f16x8*)&Ws[col * XP + seg * 8] =
                *(const f16x8*)(Wt + (size_t)col * K + kc + seg * 8);
        }
        __syncthreads();

        f16x8 a = *(const f16x8*)&Xs[(wave * 16 + m16) * XP + quad * 8];
#pragma unroll
        for (int t = 0; t < NT; t++) {
            f16x8 b = *(const f16x8*)&Ws[(t * 16 + m16) * XP + quad * 8];
            acc[t] = __builtin_amdgcn_mfma_f32_16x16x32_f16(a, b, acc[t], 0, 0, 0);
        }
        __syncthreads();
    }

#pragma unroll
    for (int t = 0; t < NT; t++) {
#pragma unroll
        for (int r = 0; r < 4; r++) {
            int row = wave * 16 + quad * 4 + r;
            Hs[row * HP + t * 16 + m16] = (_Float16)acc[t][r];
        }
    }
    __syncthreads();

    for (int u = tid; u < 64 * NOUT / 8; u += 256) {
        int row = u / (NOUT / 8), seg = u % (NOUT / 8);
        int gn = nb + row;
        if (gn < n)
            *(f16x8*)(h + (size_t)gn * NOUT + seg * 8) =
                *(const f16x8*)&Hs[row * HP + seg * 8];
    }

    {
        int node = tid >> 2, head = tid & 3;
        int gn = nb + node;
        const _Float16* hr = &Hs[node * HP + head * C];
        float s1 = 0.f, s2 = 0.f;
#pragma unroll 4
        for (int c = 0; c < C; c++) {
            float v = (float)hr[c];
            s1 += v * As[head * C + c];
            s2 += v * Ad[head * C + c];
        }
        if (gn < n) {
            a_s[gn * 4 + head] = s1;
            a_d[gn * 4 + head] = s2;
        }
    }
}

// ---------------------------------------------------------------------------
// SINGLE-SWEEP fused softmax+aggregation, F = 128 (layers 2/3). 32 thr/node,
// 8 nodes/block; 16-deep gather pipeline (+4-deep and scalar remainders).
// MODE 0: +bias, ELU -> fp16. MODE 1: head-mean, +bias -> fp32.
// ---------------------------------------------------------------------------
template <int MODE>
__global__ __launch_bounds__(256) void gat_agg128_kernel(
    const int* __restrict__ start, const unsigned short* __restrict__ ss,
    const __half* __restrict__ h, const float* __restrict__ a_s,
    const float* __restrict__ a_d, const float* __restrict__ bias,
    void* __restrict__ out, int n)
{
    int local = threadIdx.x >> 5;
    int q     = threadIdx.x & 31;
    int node  = blockIdx.x * 8 + local;
    bool active = node < n;
    int s0 = 0, s1 = 0;
    if (active) { s0 = start[node]; s1 = start[node + 1]; }
    int head = q >> 3;
    float adh = active ? a_d[node * 4 + head] : 0.f;
    const float2* __restrict__ h2 = (const float2*)h + q;

    float4 acc = make_float4(0.f, 0.f, 0.f, 0.f);
    float sm = 0.f;
    int i = s0;
    for (; i + 16 <= s1; i += 16) {
        int    sj[16];
        float  ej[16];
        float2 rj[16];
#pragma unroll
        for (int j = 0; j < 16; j++) sj[j] = (int)ss[i + j];
#pragma unroll
        for (int j = 0; j < 16; j++) ej[j] = a_s[sj[j] * 4 + head];
#pragma unroll
        for (int j = 0; j < 16; j++) rj[j] = h2[(size_t)sj[j] * 32];
#pragma unroll
        for (int j = 0; j < 16; j++) {
            float e = ej[j] + adh;
            e = e > 0.f ? e : NEG_SLOPE * e;
            float p = __expf(e);
            sm += p;
            h4u u; u.f2 = rj[j];
            float2 lo = __half22float2(u.h2[0]);
            float2 hi = __half22float2(u.h2[1]);
            acc.x += lo.x * p; acc.y += lo.y * p;
            acc.z += hi.x * p; acc.w += hi.y * p;
        }
    }
    for (; i + 4 <= s1; i += 4) {
        int    sj[4];
        float  ej[4];
        float2 rj[4];
#pragma unroll
        for (int j = 0; j < 4; j++) sj[j] = (int)ss[i + j];
#pragma unroll
        for (int j = 0; j < 4; j++) ej[j] = a_s[sj[j] * 4 + head];
#pragma unroll
        for (int j = 0; j < 4; j++) rj[j] = h2[(size_t)sj[j] * 32];
#pragma unroll
        for (int j = 0; j < 4; j++) {
            float e = ej[j] + adh;
            e = e > 0.f ? e : NEG_SLOPE * e;
            float p = __expf(e);
            sm += p;
            h4u u; u.f2 = rj[j];
            float2 lo = __half22float2(u.h2[0]);
            float2 hi = __half22float2(u.h2[1]);
            acc.x += lo.x * p; acc.y += lo.y * p;
            acc.z += hi.x * p; acc.w += hi.y * p;
        }
    }
    for (; i < s1; i++) {
        int s = (int)ss[i];
        float e = a_s[s * 4 + head] + adh;
        e = e > 0.f ? e : NEG_SLOPE * e;
        float p = __expf(e);
        sm += p;
        h4u u; u.f2 = h2[(size_t)s * 32];
        float2 lo = __half22float2(u.h2[0]);
        float2 hi = __half22float2(u.h2[1]);
        acc.x += lo.x * p; acc.y += lo.y * p;
        acc.z += hi.x * p; acc.w += hi.y * p;
    }

    float inv = 1.f / (sm + 1e-16f);
    acc.x *= inv; acc.y *= inv; acc.z *= inv; acc.w *= inv;

    if (MODE == 0) {
        if (active) {
            float4 b4 = ((const float4*)bias)[q];
            float4 v = make_float4(acc.x + b4.x, acc.y + b4.y, acc.z + b4.z,
                                   acc.w + b4.w);
            v.x = v.x > 0.f ? v.x : (__expf(v.x) - 1.f);
            v.y = v.y > 0.f ? v.y : (__expf(v.y) - 1.f);
            v.z = v.z > 0.f ? v.z : (__expf(v.z) - 1.f);
            v.w = v.w > 0.f ? v.w : (__expf(v.w) - 1.f);
            h4u u;
            u.h2[0] = __floats2half2_rn(v.x, v.y);
            u.h2[1] = __floats2half2_rn(v.z, v.w);
            *(float2*)((__half*)out + (size_t)node * 128 + q * 4) = u.f2;
        }
    } else {
        __shared__ float4 sh4[8][33];
        sh4[local][q] = acc;
        __syncthreads();
        if (q < 8 && active) {
            float4 a = sh4[local][q];
            float4 b = sh4[local][q + 8];
            float4 c = sh4[local][q + 16];
            float4 d = sh4[local][q + 24];
            float4 b4 = ((const float4*)bias)[q];
            float4 r = make_float4(0.25f * (a.x + b.x + c.x + d.x) + b4.x,
                                   0.25f * (a.y + b.y + c.y + d.y) + b4.y,
                                   0.25f * (a.z + b.z + c.z + d.z) + b4.z,
                                   0.25f * (a.w + b.w + c.w + d.w) + b4.w);
            *(float4*)((float*)out + (size_t)node * 32 + q * 4) = r;
        }
    }
}

// ---------------------------------------------------------------------------
// SINGLE-SWEEP fused softmax+aggregation, F = 32 (layer 1). 8 thr/node,
// 32 nodes/block, 16-deep pipeline, fp16 out.
// ---------------------------------------------------------------------------
__global__ __launch_bounds__(256) void gat_agg32_kernel(
    const int* __restrict__ start, const unsigned short* __restrict__ ss,
    const __half* __restrict__ h, const float* __restrict__ a_s,
    const float* __restrict__ a_d, const float* __restrict__ bias,
    __half* __restrict__ out, int n)
{
    int local = threadIdx.x >> 3;
    int q     = threadIdx.x & 7;
    int node  = blockIdx.x * 32 + local;
    bool active = node < n;
    int s0 = 0, s1 = 0;
    if (active) { s0 = start[node]; s1 = start[node + 1]; }
    int head = q >> 1;
    float adh = active ? a_d[node * 4 + head] : 0.f;
    const float2* __restrict__ h2 = (const float2*)h + q;

    float4 acc = make_float4(0.f, 0.f, 0.f, 0.f);
    float sm = 0.f;
    int i = s0;
    for (; i + 16 <= s1; i += 16) {
        int    sj[16];
        float  ej[16];
        float2 rj[16];
#pragma unroll
        for (int j = 0; j < 16; j++) sj[j] = (int)ss[i + j];
#pragma unroll
        for (int j = 0; j < 16; j++) ej[j] = a_s[sj[j] * 4 + head];
#pragma unroll
        for (int j = 0; j < 16; j++) rj[j] = h2[(size_t)sj[j] * 8];
#pragma unroll
        for (int j = 0; j < 16; j++) {
            float e = ej[j] + adh;
            e = e > 0.f ? e : NEG_SLOPE * e;
            float p = __expf(e);
            sm += p;
            h4u u; u.f2 = rj[j];
            float2 lo = __half22float2(u.h2[0]);
            float2 hi = __half22float2(u.h2[1]);
            acc.x += lo.x * p; acc.y += lo.y * p;
            acc.z += hi.x * p; acc.w += hi.y * p;
        }
    }
    for (; i + 4 <= s1; i += 4) {
        int    sj[4];
        float  ej[4];
        float2 rj[4];
#pragma unroll
        for (int j = 0; j < 4; j++) sj[j] = (int)ss[i + j];
#pragma unroll
        for (int j = 0; j < 4; j++) ej[j] = a_s[sj[j] * 4 + head];
#pragma unroll
        for (int j = 0; j < 4; j++) rj[j] = h2[(size_t)sj[j] * 8];
#pragma unroll
        for (int j = 0; j < 4; j++) {
            float e = ej[j] + adh;
            e = e > 0.f ? e : NEG_SLOPE * e;
            float p = __expf(e);
            sm += p;
            h4u u; u.f2 = rj[j];
            float2 lo = __half22float2(u.h2[0]);
            float2 hi = __half22float2(u.h2[1]);
            acc.x += lo.x * p; acc.y += lo.y * p;
            acc.z += hi.x * p; acc.w += hi.y * p;
        }
    }
    for (; i < s1; i++) {
        int s = (int)ss[i];
        float e = a_s[s * 4 + head] + adh;
        e = e > 0.f ? e : NEG_SLOPE * e;
        float p = __expf(e);
        sm += p;
        h4u u; u.f2 = h2[(size_t)s * 8];
        float2 lo = __half22float2(u.h2[0]);
        float2 hi = __half22float2(u.h2[1]);
        acc.x += lo.x * p; acc.y += lo.y * p;
        acc.z += hi.x * p; acc.w += hi.y * p;
    }

    if (active) {
        float inv = 1.f / (sm + 1e-16f);
        float4 b4 = ((const float4*)bias)[q];
        float4 v = make_float4(acc.x * inv + b4.x, acc.y * inv + b4.y,
                               acc.z * inv + b4.z, acc.w * inv + b4.w);
        v.x = v.x > 0.f ? v.x : (__expf(v.x) - 1.f);
        v.y = v.y > 0.f ? v.y : (__expf(v.y) - 1.f);
        v.z = v.z > 0.f ? v.z : (__expf(v.z) - 1.f);
        v.w = v.w > 0.f ? v.w : (__expf(v.w) - 1.f);
        h4u u;
        u.h2[0] = __floats2half2_rn(v.x, v.y);
        u.h2[1] = __floats2half2_rn(v.z, v.w);
        *(float2*)(out + (size_t)node * 32 + q * 4) = u.f2;
    }
}

// ---------------------------------------------------------------------------

extern "C" void kernel_launch(void* const* d_in, const int* in_sizes, int n_in,
                              void* d_out, int out_size, void* d_ws, size_t ws_size,
                              hipStream_t stream)
{
    const float* x   = (const float*)d_in[0];
    const void*  ei  = d_in[1];
    const float* W1  = (const float*)d_in[2];
    const float* as1 = (const float*)d_in[3];
    const float* ad1 = (const float*)d_in[4];
    const float* b1  = (const float*)d_in[5];
    const float* W2  = (const float*)d_in[6];
    const float* as2 = (const float*)d_in[7];
    const float* ad2 = (const float*)d_in[8];
    const float* b2  = (const float*)d_in[9];
    const float* W3  = (const float*)d_in[10];
    const float* as3 = (const float*)d_in[11];
    const float* ad3 = (const float*)d_in[12];
    const float* b3  = (const float*)d_in[13];
    float* out = (float*)d_out;

    const int N_ = in_sizes[0] / 128;
    const int E_ = in_sizes[1] / 2;

    char* ws = (char*)d_ws;
    size_t off = 0;
    auto alloc = [&](size_t nbytes) -> void* {
        void* p = ws + off;
        off += (nbytes + 255) & ~(size_t)255;
        return p;
    };
    __half* h          = (__half*)alloc((size_t)N_ * 128 * 2);
    __half* x2h        = (__half*)alloc((size_t)N_ * 32 * 2);
    __half* x3h        = (__half*)alloc((size_t)N_ * 128 * 2);
    __half* Wt1        = (__half*)alloc(128 * 32 * 2);
    __half* Wt2        = (__half*)alloc(32 * 128 * 2);
    __half* Wt3        = (__half*)alloc(128 * 128 * 2);
    float* asrc        = (float*)alloc((size_t)N_ * 4 * 4);
    float* adst        = (float*)alloc((size_t)N_ * 4 * 4);
    int*   deg         = (int*)alloc((size_t)N_ * 4);
    int*   start       = (int*)alloc((size_t)(N_ + 1) * 4);
    unsigned short* sorted_src = (unsigned short*)alloc((size_t)E_ * 2);
    unsigned short* s16        = (unsigned short*)alloc((size_t)E_ * 2);
    unsigned short* d16        = (unsigned short*)alloc((size_t)E_ * 2);
    unsigned short* r16        = (unsigned short*)alloc((size_t)E_ * 2);
    int*   bsum        = (int*)alloc(4096);
    int*   flag        = (int*)alloc(256);

    const int gN8  = cdiv(N_, 8);
    const int gN32 = cdiv(N_, 32);
    const int gN64 = cdiv(N_, 64);
    const int nSB  = cdiv(N_, 1024);
    int prepWork = N_ > 128 * 128 ? N_ : 128 * 128;

    // ---- Prep + CSR build (5 small dispatches — beats cooperative sync) ----
    prep_kernel<<<cdiv(prepWork, 256), 256, 0, stream>>>(ei, E_, N_, flag, deg,
                                                         W1, Wt1, W2, Wt2, W3, Wt3);
    hist_kernel<<<cdiv(E_, 1024), 256, 0, stream>>>(ei, flag, deg, s16, d16, r16, E_);
    scan_part_kernel<<<nSB, 1024, 0, stream>>>(deg, start, bsum, N_);
    scan_add_kernel<<<nSB, 1024, 0, stream>>>(deg, bsum, start, N_);
    scatter_kernel<<<cdiv(E_, 1024), 256, 0, stream>>>(s16, d16, r16, start,
                                                       sorted_src, E_);

    // ---- Layer 1: 128 -> [4,8] concat=32, ELU ----
    gemm_mfma_kernel<128, 32, 0><<<gN64, 256, 0, stream>>>(x, Wt1, as1, ad1, h,
                                                           asrc, adst, N_);
    gat_agg32_kernel<<<gN32, 256, 0, stream>>>(start, sorted_src, h, asrc, adst, b1,
                                               x2h, N_);

    // ---- Layer 2: 32 -> [4,32] concat=128, ELU ----
    gemm_mfma_kernel<32, 128, 1><<<gN64, 256, 0, stream>>>(x2h, Wt2, as2, ad2, h,
                                                           asrc, adst, N_);
    gat_agg128_kernel<0><<<gN8, 256, 0, stream>>>(start, sorted_src, h, asrc, adst, b2,
                                                  x3h, N_);

    // ---- Layer 3: 128 -> [4,32] mean=32 ----
    gemm_mfma_kernel<128, 128, 1><<<gN64, 256, 0, stream>>>(x3h, Wt3, as3, ad3, h,
                                                            asrc, adst, N_);
    gat_agg128_kernel<1><<<gN8, 256, 0, stream>>>(start, sorted_src, h, asrc, adst, b3,
                                                  out, N_);
}

// Round 15
// 282.523 us; speedup vs baseline: 2.0903x; 1.0199x over previous
//
#include <hip/hip_runtime.h>
#include <hip/hip_fp16.h>

#define NEG_SLOPE 0.2f

static inline int cdiv(long long a, long long b) { return (int)((a + b - 1) / b); }

typedef _Float16 f16x8 __attribute__((ext_vector_type(8)));
typedef float f32x4 __attribute__((ext_vector_type(4)));

union h4u {
    float2  f2;
    __half2 h2[2];
};
union h8u {
    f16x8   v;
    __half2 h2[4];
};

__device__ __forceinline__ void load_sd(const void* ei_raw, int is64, int e, int E_,
                                        int& s, int& d)
{
    if (is64) {
        const long long* p = (const long long*)ei_raw;
        s = (int)p[e];
        d = (int)p[E_ + e];
    } else {
        const int* p = (const int*)ei_raw;
        s = p[e];
        d = p[E_ + e];
    }
}

// ---------------------------------------------------------------------------
// PREP: int64 probe (block 0), deg zero-init, W fp32->fp16 transposes.
// (Round-13 lesson: separate small dispatches beat cooperative grid.sync.)
// ---------------------------------------------------------------------------
__global__ __launch_bounds__(256) void prep_kernel(
    const void* __restrict__ ei, int E_, int n, int* __restrict__ flag,
    int* __restrict__ deg,
    const float* __restrict__ W1, __half* __restrict__ Wt1,
    const float* __restrict__ W2, __half* __restrict__ Wt2,
    const float* __restrict__ W3, __half* __restrict__ Wt3)
{
    int idx = blockIdx.x * 256 + threadIdx.x;

    if (blockIdx.x == 0) {
        __shared__ int bad;
        if (threadIdx.x == 0) bad = 0;
        __syncthreads();
        const long long* e64 = (const long long*)ei;
        int cnt = E_ < 512 ? E_ : 512;
        bool ok = true;
        for (int i = threadIdx.x; i < cnt; i += 256) {
            long long v = e64[i];
            if (v < 0 || v >= n) ok = false;
        }
        if (!ok) atomicAdd(&bad, 1);
        __syncthreads();
        if (threadIdx.x == 0) *flag = (bad == 0) ? 1 : 0;
    }

    if (idx < n) deg[idx] = 0;

    if (idx < 128 * 32) {
        int k = idx / 32, c = idx % 32;
        Wt1[c * 128 + k] = __float2half(W1[idx]);
    }
    if (idx < 32 * 128) {
        int k = idx / 128, c = idx % 128;
        Wt2[c * 32 + k] = __float2half(W2[idx]);
    }
    if (idx < 128 * 128) {
        int k = idx / 128, c = idx % 128;
        Wt3[c * 128 + k] = __float2half(W3[idx]);
    }
}

// ---------------------------------------------------------------------------
// CSR build — ushort edge arrays; rank saved in hist -> atomic-free scatter.
// ---------------------------------------------------------------------------
__global__ __launch_bounds__(256) void hist_kernel(const void* __restrict__ ei_raw,
                                                   const int* __restrict__ flag,
                                                   int* __restrict__ deg,
                                                   unsigned short* __restrict__ s16,
                                                   unsigned short* __restrict__ d16,
                                                   unsigned short* __restrict__ r16,
                                                   int E_)
{
    int base = blockIdx.x * 1024 + threadIdx.x;
    int is64 = *flag;
    int sj[4], dj[4], rj[4];
    bool v[4];
#pragma unroll
    for (int j = 0; j < 4; j++) {
        int e = base + j * 256;
        v[j] = e < E_;
        if (v[j]) load_sd(ei_raw, is64, e, E_, sj[j], dj[j]);
    }
#pragma unroll
    for (int j = 0; j < 4; j++) {
        int e = base + j * 256;
        if (v[j]) {
            s16[e] = (unsigned short)sj[j];
            d16[e] = (unsigned short)dj[j];
        }
    }
#pragma unroll
    for (int j = 0; j < 4; j++) {
        if (v[j]) rj[j] = atomicAdd(deg + dj[j], 1);
    }
#pragma unroll
    for (int j = 0; j < 4; j++) {
        int e = base + j * 256;
        if (v[j]) r16[e] = (unsigned short)rj[j];
    }
}

__device__ __forceinline__ int wave_incl_scan(int v)
{
    int lane = threadIdx.x & 63;
#pragma unroll
    for (int off = 1; off < 64; off <<= 1) {
        int t = __shfl_up(v, off);
        if (lane >= off) v += t;
    }
    return v;
}

__global__ __launch_bounds__(1024) void scan_part_kernel(const int* __restrict__ deg,
                                                         int* __restrict__ start,
                                                         int* __restrict__ bsum, int n)
{
    __shared__ int wsum[16];
    int i = blockIdx.x * 1024 + threadIdx.x;
    int wid = threadIdx.x >> 6, lane = threadIdx.x & 63;
    int v = (i < n) ? deg[i] : 0;
    int incl = wave_incl_scan(v);
    if (lane == 63) wsum[wid] = incl;
    __syncthreads();
    if (wid == 0) {
        int w = (lane < 16) ? wsum[lane] : 0;
        w = wave_incl_scan(w);
        if (lane < 16) wsum[lane] = w;
    }
    __syncthreads();
    int excl = incl - v + (wid ? wsum[wid - 1] : 0);
    if (i < n) start[i] = excl;
    if (threadIdx.x == 1023) bsum[blockIdx.x] = wsum[15];
}

__global__ __launch_bounds__(1024) void scan_add_kernel(const int* __restrict__ deg,
                                                        const int* __restrict__ bsum,
                                                        int* __restrict__ start, int n)
{
    __shared__ int off_sh;
    if (threadIdx.x == 0) {
        int s = 0;
        for (int j = 0; j < blockIdx.x; j++) s += bsum[j];
        off_sh = s;
    }
    __syncthreads();
    int i = blockIdx.x * 1024 + threadIdx.x;
    if (i >= n) return;
    int v = start[i] + off_sh;
    start[i] = v;
    if (i == n - 1) start[n] = v + deg[i];
}

__global__ __launch_bounds__(256) void scatter_kernel(
    const unsigned short* __restrict__ s16, const unsigned short* __restrict__ d16,
    const unsigned short* __restrict__ r16, const int* __restrict__ start,
    unsigned short* __restrict__ sorted_src, int E_)
{
    int base = blockIdx.x * 1024 + threadIdx.x;
    int sj[4], dj[4], rj[4];
    bool v[4];
#pragma unroll
    for (int j = 0; j < 4; j++) {
        int e = base + j * 256;
        v[j] = e < E_;
        sj[j] = v[j] ? (int)s16[e] : 0;
        dj[j] = v[j] ? (int)d16[e] : 0;
        rj[j] = v[j] ? (int)r16[e] : 0;
    }
    int pj[4];
#pragma unroll
    for (int j = 0; j < 4; j++) {
        if (v[j]) pj[j] = start[dj[j]] + rj[j];
    }
#pragma unroll
    for (int j = 0; j < 4; j++) {
        if (v[j])
            __builtin_nontemporal_store((unsigned short)sj[j], sorted_src + pj[j]);
    }
}

// ---------------------------------------------------------------------------
// MFMA GEMM + fused attention epilogue (Round-10 structure, verified).
// A16=0: stage A from fp32 with in-register convert (layer 1).
// ---------------------------------------------------------------------------
template <int K, int NOUT, int A16>
__global__ __launch_bounds__(256) void gemm_mfma_kernel(
    const void* __restrict__ xin, const __half* __restrict__ Wt,
    const float* __restrict__ att_s, const float* __restrict__ att_d,
    __half* __restrict__ h, float* __restrict__ a_s, float* __restrict__ a_d, int n)
{
    constexpr int KC = 32;
    constexpr int NT = NOUT / 16;
    constexpr int XP = KC + 8;
    constexpr int HP = NOUT + 8;
    constexpr int C  = NOUT / 4;

    __shared__ _Float16 Xs[64 * XP];
    __shared__ _Float16 Ws[NOUT * XP];
    __shared__ _Float16 Hs[64 * HP];
    __shared__ float As[NOUT], Ad[NOUT];

    const int tid  = threadIdx.x;
    const int nb   = blockIdx.x * 64;
    const int wave = tid >> 6, lane = tid & 63;
    const int m16  = lane & 15, quad = lane >> 4;

    if (tid < NOUT) { As[tid] = att_s[tid]; Ad[tid] = att_d[tid]; }

    f32x4 acc[NT];
#pragma unroll
    for (int t = 0; t < NT; t++) acc[t] = (f32x4){0.f, 0.f, 0.f, 0.f};

    for (int kc = 0; kc < K; kc += KC) {
        {
            int node = tid >> 2, seg = tid & 3;
            int gn = nb + node;
            f16x8 v = {0, 0, 0, 0, 0, 0, 0, 0};
            if (gn < n) {
                if (A16) {
                    v = *(const f16x8*)((const __half*)xin + (size_t)gn * K + kc +
                                        seg * 8);
                } else {
                    const float4* p =
                        (const float4*)((const float*)xin + (size_t)gn * K + kc + seg * 8);
                    float4 a = p[0], b = p[1];
                    v = (f16x8){(_Float16)a.x, (_Float16)a.y, (_Float16)a.z,
                                (_Float16)a.w, (_Float16)b.x, (_Float16)b.y,
                                (_Float16)b.z, (_Float16)b.w};
                }
            }
            *(f16x8*)&Xs[node * XP + seg * 8] = v;
        }
        for (int u = tid; u < NOUT * 4; u += 256) {
            int col = u >> 2, seg = u & 3;
            *(f16x8*)&Ws[col * XP + seg * 8] =
                *(const f16x8*)(Wt + (size_t)col * K + kc + seg * 8);
        }
        __syncthreads();

        f16x8 a = *(const f16x8*)&Xs[(wave * 16 + m16) * XP + quad * 8];
#pragma unroll
        for (int t = 0; t < NT; t++) {
            f16x8 b = *(const f16x8*)&Ws[(t * 16 + m16) * XP + quad * 8];
            acc[t] = __builtin_amdgcn_mfma_f32_16x16x32_f16(a, b, acc[t], 0, 0, 0);
        }
        __syncthreads();
    }

#pragma unroll
    for (int t = 0; t < NT; t++) {
#pragma unroll
        for (int r = 0; r < 4; r++) {
            int row = wave * 16 + quad * 4 + r;
            Hs[row * HP + t * 16 + m16] = (_Float16)acc[t][r];
        }
    }
    __syncthreads();

    for (int u = tid; u < 64 * NOUT / 8; u += 256) {
        int row = u / (NOUT / 8), seg = u % (NOUT / 8);
        int gn = nb + row;
        if (gn < n)
            *(f16x8*)(h + (size_t)gn * NOUT + seg * 8) =
                *(const f16x8*)&Hs[row * HP + seg * 8];
    }

    {
        int node = tid >> 2, head = tid & 3;
        int gn = nb + node;
        const _Float16* hr = &Hs[node * HP + head * C];
        float s1 = 0.f, s2 = 0.f;
#pragma unroll 4
        for (int c = 0; c < C; c++) {
            float v = (float)hr[c];
            s1 += v * As[head * C + c];
            s2 += v * Ad[head * C + c];
        }
        if (gn < n) {
            a_s[gn * 4 + head] = s1;
            a_d[gn * 4 + head] = s2;
        }
    }
}

// ---------------------------------------------------------------------------
// SINGLE-SWEEP fused softmax+aggregation, F = 128 (layers 2/3).
// 16 thr/node (f16x8 = 16 B per lane per edge — HALF the memory requests of
// the 32-lane/8 B layout; request-queue is the bottleneck per Round-14),
// 16 nodes/block, 8-deep pipeline. Every lane sweeps the whole edge list, so
// sm is lane-uniform. MODE 0: +bias, ELU -> fp16. MODE 1: head-mean -> fp32.
// ---------------------------------------------------------------------------
template <int MODE>
__global__ __launch_bounds__(256) void gat_agg128_kernel(
    const int* __restrict__ start, const unsigned short* __restrict__ ss,
    const __half* __restrict__ h, const float* __restrict__ a_s,
    const float* __restrict__ a_d, const float* __restrict__ bias,
    void* __restrict__ out, int n)
{
    int local = threadIdx.x >> 4;   // node group 0..15
    int q     = threadIdx.x & 15;   // lane within group; owns features 8q..8q+7
    int node  = blockIdx.x * 16 + local;
    bool active = node < n;
    int s0 = 0, s1 = 0;
    if (active) { s0 = start[node]; s1 = start[node + 1]; }
    int head = q >> 2;
    float adh = active ? a_d[node * 4 + head] : 0.f;
    const f16x8* __restrict__ h8 = (const f16x8*)h + q;  // row = 16 units

    float acc[8];
#pragma unroll
    for (int j = 0; j < 8; j++) acc[j] = 0.f;
    float sm = 0.f;

    int i = s0;
    for (; i + 8 <= s1; i += 8) {
        int   sj[8];
        float ej[8];
        h8u   rj[8];
#pragma unroll
        for (int j = 0; j < 8; j++) sj[j] = (int)ss[i + j];
#pragma unroll
        for (int j = 0; j < 8; j++) ej[j] = a_s[sj[j] * 4 + head];
#pragma unroll
        for (int j = 0; j < 8; j++) rj[j].v = h8[(size_t)sj[j] * 16];
#pragma unroll
        for (int j = 0; j < 8; j++) {
            float e = ej[j] + adh;
            e = e > 0.f ? e : NEG_SLOPE * e;
            float p = __expf(e);
            sm += p;
#pragma unroll
            for (int k = 0; k < 4; k++) {
                float2 f = __half22float2(rj[j].h2[k]);
                acc[2 * k]     += f.x * p;
                acc[2 * k + 1] += f.y * p;
            }
        }
    }
    for (; i < s1; i++) {
        int s = (int)ss[i];
        float e = a_s[s * 4 + head] + adh;
        e = e > 0.f ? e : NEG_SLOPE * e;
        float p = __expf(e);
        sm += p;
        h8u u; u.v = h8[(size_t)s * 16];
#pragma unroll
        for (int k = 0; k < 4; k++) {
            float2 f = __half22float2(u.h2[k]);
            acc[2 * k]     += f.x * p;
            acc[2 * k + 1] += f.y * p;
        }
    }

    float inv = 1.f / (sm + 1e-16f);
#pragma unroll
    for (int j = 0; j < 8; j++) acc[j] *= inv;

    if (MODE == 0) {
        if (active) {
            h8u u;
#pragma unroll
            for (int k = 0; k < 4; k++) {
                float vx = acc[2 * k]     + bias[q * 8 + 2 * k];
                float vy = acc[2 * k + 1] + bias[q * 8 + 2 * k + 1];
                vx = vx > 0.f ? vx : (__expf(vx) - 1.f);
                vy = vy > 0.f ? vy : (__expf(vy) - 1.f);
                u.h2[k] = __floats2half2_rn(vx, vy);
            }
            *(f16x8*)((__half*)out + (size_t)node * 128 + q * 8) = u.v;
        }
    } else {
        __shared__ float sh[16][132];
#pragma unroll
        for (int j = 0; j < 8; j++) sh[local][q * 8 + j] = acc[j];
        __syncthreads();
        if (q < 4 && active) {
            // lane q handles output features 8q..8q+7 (mean over 4 heads)
            float r[8];
#pragma unroll
            for (int j = 0; j < 8; j++) {
                int c = q * 8 + j;
                r[j] = 0.25f * (sh[local][c] + sh[local][32 + c] + sh[local][64 + c] +
                                sh[local][96 + c]) + bias[c];
            }
            float4* o4 = (float4*)((float*)out + (size_t)node * 32 + q * 8);
            o4[0] = make_float4(r[0], r[1], r[2], r[3]);
            o4[1] = make_float4(r[4], r[5], r[6], r[7]);
        }
    }
}

// ---------------------------------------------------------------------------
// SINGLE-SWEEP fused softmax+aggregation, F = 32 (layer 1). 4 thr/node
// (f16x8 per lane = full head row, 4 requests/edge vs 8), 64 nodes/block,
// 8-deep pipeline, fp16 out. head = q.
// ---------------------------------------------------------------------------
__global__ __launch_bounds__(256) void gat_agg32_kernel(
    const int* __restrict__ start, const unsigned short* __restrict__ ss,
    const __half* __restrict__ h, const float* __restrict__ a_s,
    const float* __restrict__ a_d, const float* __restrict__ bias,
    __half* __restrict__ out, int n)
{
    int local = threadIdx.x >> 2;   // node group 0..63
    int q     = threadIdx.x & 3;    // lane = head; owns features 8q..8q+7
    int node  = blockIdx.x * 64 + local;
    bool active = node < n;
    int s0 = 0, s1 = 0;
    if (active) { s0 = start[node]; s1 = start[node + 1]; }
    float adh = active ? a_d[node * 4 + q] : 0.f;
    const f16x8* __restrict__ h8 = (const f16x8*)h + q;  // row = 4 units

    float acc[8];
#pragma unroll
    for (int j = 0; j < 8; j++) acc[j] = 0.f;
    float sm = 0.f;

    int i = s0;
    for (; i + 8 <= s1; i += 8) {
        int   sj[8];
        float ej[8];
        h8u   rj[8];
#pragma unroll
        for (int j = 0; j < 8; j++) sj[j] = (int)ss[i + j];
#pragma unroll
        for (int j = 0; j < 8; j++) ej[j] = a_s[sj[j] * 4 + q];
#pragma unroll
        for (int j = 0; j < 8; j++) rj[j].v = h8[(size_t)sj[j] * 4];
#pragma unroll
        for (int j = 0; j < 8; j++) {
            float e = ej[j] + adh;
            e = e > 0.f ? e : NEG_SLOPE * e;
            float p = __expf(e);
            sm += p;
#pragma unroll
            for (int k = 0; k < 4; k++) {
                float2 f = __half22float2(rj[j].h2[k]);
                acc[2 * k]     += f.x * p;
                acc[2 * k + 1] += f.y * p;
            }
        }
    }
    for (; i < s1; i++) {
        int s = (int)ss[i];
        float e = a_s[s * 4 + q] + adh;
        e = e > 0.f ? e : NEG_SLOPE * e;
        float p = __expf(e);
        sm += p;
        h8u u; u.v = h8[(size_t)s * 4];
#pragma unroll
        for (int k = 0; k < 4; k++) {
            float2 f = __half22float2(u.h2[k]);
            acc[2 * k]     += f.x * p;
            acc[2 * k + 1] += f.y * p;
        }
    }

    if (active) {
        float inv = 1.f / (sm + 1e-16f);
        h8u u;
#pragma unroll
        for (int k = 0; k < 4; k++) {
            float vx = acc[2 * k] * inv     + bias[q * 8 + 2 * k];
            float vy = acc[2 * k + 1] * inv + bias[q * 8 + 2 * k + 1];
            vx = vx > 0.f ? vx : (__expf(vx) - 1.f);
            vy = vy > 0.f ? vy : (__expf(vy) - 1.f);
            u.h2[k] = __floats2half2_rn(vx, vy);
        }
        *(f16x8*)(out + (size_t)node * 32 + q * 8) = u.v;
    }
}

// ---------------------------------------------------------------------------

extern "C" void kernel_launch(void* const* d_in, const int* in_sizes, int n_in,
                              void* d_out, int out_size, void* d_ws, size_t ws_size,
                              hipStream_t stream)
{
    const float* x   = (const float*)d_in[0];
    const void*  ei  = d_in[1];
    const float* W1  = (const float*)d_in[2];
    const float* as1 = (const float*)d_in[3];
    const float* ad1 = (const float*)d_in[4];
    const float* b1  = (const float*)d_in[5];
    const float* W2  = (const float*)d_in[6];
    const float* as2 = (const float*)d_in[7];
    const float* ad2 = (const float*)d_in[8];
    const float* b2  = (const float*)d_in[9];
    const float* W3  = (const float*)d_in[10];
    const float* as3 = (const float*)d_in[11];
    const float* ad3 = (const float*)d_in[12];
    const float* b3  = (const float*)d_in[13];
    float* out = (float*)d_out;

    const int N_ = in_sizes[0] / 128;
    const int E_ = in_sizes[1] / 2;

    char* ws = (char*)d_ws;
    size_t off = 0;
    auto alloc = [&](size_t nbytes) -> void* {
        void* p = ws + off;
        off += (nbytes + 255) & ~(size_t)255;
        return p;
    };
    __half* h          = (__half*)alloc((size_t)N_ * 128 * 2);
    __half* x2h        = (__half*)alloc((size_t)N_ * 32 * 2);
    __half* x3h        = (__half*)alloc((size_t)N_ * 128 * 2);
    __half* Wt1        = (__half*)alloc(128 * 32 * 2);
    __half* Wt2        = (__half*)alloc(32 * 128 * 2);
    __half* Wt3        = (__half*)alloc(128 * 128 * 2);
    float* asrc        = (float*)alloc((size_t)N_ * 4 * 4);
    float* adst        = (float*)alloc((size_t)N_ * 4 * 4);
    int*   deg         = (int*)alloc((size_t)N_ * 4);
    int*   start       = (int*)alloc((size_t)(N_ + 1) * 4);
    unsigned short* sorted_src = (unsigned short*)alloc((size_t)E_ * 2);
    unsigned short* s16        = (unsigned short*)alloc((size_t)E_ * 2);
    unsigned short* d16        = (unsigned short*)alloc((size_t)E_ * 2);
    unsigned short* r16        = (unsigned short*)alloc((size_t)E_ * 2);
    int*   bsum        = (int*)alloc(4096);
    int*   flag        = (int*)alloc(256);

    const int gN16 = cdiv(N_, 16);   // agg128: 16 nodes/block
    const int gN64 = cdiv(N_, 64);   // gemm blocks; agg32: 64 nodes/block
    const int nSB  = cdiv(N_, 1024);
    int prepWork = N_ > 128 * 128 ? N_ : 128 * 128;

    // ---- Prep + CSR build (5 small dispatches) ----
    prep_kernel<<<cdiv(prepWork, 256), 256, 0, stream>>>(ei, E_, N_, flag, deg,
                                                         W1, Wt1, W2, Wt2, W3, Wt3);
    hist_kernel<<<cdiv(E_, 1024), 256, 0, stream>>>(ei, flag, deg, s16, d16, r16, E_);
    scan_part_kernel<<<nSB, 1024, 0, stream>>>(deg, start, bsum, N_);
    scan_add_kernel<<<nSB, 1024, 0, stream>>>(deg, bsum, start, N_);
    scatter_kernel<<<cdiv(E_, 1024), 256, 0, stream>>>(s16, d16, r16, start,
                                                       sorted_src, E_);

    // ---- Layer 1: 128 -> [4,8] concat=32, ELU ----
    gemm_mfma_kernel<128, 32, 0><<<gN64, 256, 0, stream>>>(x, Wt1, as1, ad1, h,
                                                           asrc, adst, N_);
    gat_agg32_kernel<<<gN64, 256, 0, stream>>>(start, sorted_src, h, asrc, adst, b1,
                                               x2h, N_);

    // ---- Layer 2: 32 -> [4,32] concat=128, ELU ----
    gemm_mfma_kernel<32, 128, 1><<<gN64, 256, 0, stream>>>(x2h, Wt2, as2, ad2, h,
                                                           asrc, adst, N_);
    gat_agg128_kernel<0><<<gN16, 256, 0, stream>>>(start, sorted_src, h, asrc, adst, b2,
                                                   x3h, N_);

    // ---- Layer 3: 128 -> [4,32] mean=32 ----
    gemm_mfma_kernel<128, 128, 1><<<gN64, 256, 0, stream>>>(x3h, Wt3, as3, ad3, h,
                                                            asrc, adst, N_);
    gat_agg128_kernel<1><<<gN16, 256, 0, stream>>>(start, sorted_src, h, asrc, adst, b3,
                                                   out, N_);
}